// Round 5
// baseline (123.542 us; speedup 1.0000x reference)
//
#include <hip/hip_runtime.h>
#include <hip/hip_bf16.h>
#include <math.h>

#define NROWS 8192
#define DIM   256
#define INV_T 14.285714285714286f   // 1/0.07
#define LOG2E_T 20.60992893360759f  // (1/0.07) * log2(e) -- folded into un
#define EPS_N 1e-8f

typedef __attribute__((ext_vector_type(8))) short short8;
typedef __attribute__((ext_vector_type(4))) float f32x4;

typedef const __attribute__((address_space(1))) void g_void;
typedef __attribute__((address_space(3))) void l_void;

__device__ inline unsigned short f2bf(float x) {
    __hip_bfloat16 h = __float2bfloat16(x);
    return __builtin_bit_cast(unsigned short, h);
}

// ---------------------------------------------------------------------------
// Kernel 1: per-row normalize. un scaled by 1/T*log2(e) (exp2 domain for the
// GEMM); vn plain normalized; diag logit fp32 (natural-log domain); zero rowsum.
// ---------------------------------------------------------------------------
__global__ __launch_bounds__(256) void norm_kernel(
    const float* __restrict__ u, const float* __restrict__ v,
    unsigned short* __restrict__ un, unsigned short* __restrict__ vn,
    float* __restrict__ diag, float* __restrict__ rowsum)
{
    if (threadIdx.x < 4) rowsum[blockIdx.x * 4 + threadIdx.x] = 0.0f;

    const int wid  = threadIdx.x >> 6;
    const int lane = threadIdx.x & 63;
    const int r    = blockIdx.x * 4 + wid;

    const float4* u4 = (const float4*)(u + (size_t)r * DIM);
    const float4* v4 = (const float4*)(v + (size_t)r * DIM);
    float4 a = u4[lane];
    float4 b = v4[lane];

    float ssu = a.x * a.x + a.y * a.y + a.z * a.z + a.w * a.w;
    float ssv = b.x * b.x + b.y * b.y + b.z * b.z + b.w * b.w;
    float duv = a.x * b.x + a.y * b.y + a.z * b.z + a.w * b.w;

    #pragma unroll
    for (int m = 32; m >= 1; m >>= 1) {
        ssu += __shfl_xor(ssu, m);
        ssv += __shfl_xor(ssv, m);
        duv += __shfl_xor(duv, m);
    }

    const float iu  = 1.0f / fmaxf(sqrtf(ssu), EPS_N);
    const float iv  = 1.0f / fmaxf(sqrtf(ssv), EPS_N);
    const float ius = iu * LOG2E_T;          // exp2-domain scale folded into un

    ushort4 pu, pv;
    pu.x = f2bf(a.x * ius); pu.y = f2bf(a.y * ius);
    pu.z = f2bf(a.z * ius); pu.w = f2bf(a.w * ius);
    pv.x = f2bf(b.x * iv);  pv.y = f2bf(b.y * iv);
    pv.z = f2bf(b.z * iv);  pv.w = f2bf(b.w * iv);
    *(ushort4*)(un + (size_t)r * DIM + 4 * lane) = pu;
    *(ushort4*)(vn + (size_t)r * DIM + 4 * lane) = pv;

    if (lane == 0) diag[r] = duv * iu * iv * INV_T;
}

// ---------------------------------------------------------------------------
// Kernel 2: flash-style. Block = 128 i-rows x 1024 j-cols (16 tiles of 64).
// A-frags in VGPRs. LDS caps us at 2 blocks/CU anyway, so we pin the
// allocator's occupancy target with amdgpu_waves_per_eu(2,2): register
// budget 256/wave, no incentive to shrink to 96 and spill (round-3/4 bug).
// B tile staged via global_load_lds into k-chunked Bs[kg][row][8]
// (conflict-free b128 reads, measured 0 conflicts). Per wave per j-step:
// 16 ds_read_b128 + 64 MFMA + 32 exp2. One reduce+atomic per block.
// ---------------------------------------------------------------------------
__global__ __launch_bounds__(256)
__attribute__((amdgpu_waves_per_eu(2, 2)))
void gemm_kernel(
    const unsigned short* __restrict__ un, const unsigned short* __restrict__ vn,
    float* __restrict__ rowsum)
{
    __shared__ unsigned short Bs[2][32][64][8];   // 64 KB

    const int t    = threadIdx.x;
    const int lane = t & 63;
    const int wid  = t >> 6;
    const int wr   = wid >> 1;
    const int wc   = wid & 1;
    const int bid  = blockIdx.x;
    const int by   = bid & 7;          // XCD id -> j-panel pinned to one L2
    const int bx   = bid >> 3;
    const int i0   = bx * 128;
    const int j0   = by * 1024;

    const int lr = lane & 15;          // frag row (A) / frag col (B, C/D)
    const int lg = lane >> 4;          // k-group

    // ---- A fragments: rows i0+wr*64+m*16+lr, k = k*32 + lg*8 .. +7 ----
    // keep-alive pins each frag so the loads can't be sunk into the j-loop.
    short8 av[4][8];
    #pragma unroll
    for (int m = 0; m < 4; ++m) {
        const unsigned short* ar =
            un + (size_t)(i0 + wr * 64 + m * 16 + lr) * DIM + lg * 8;
        #pragma unroll
        for (int k = 0; k < 8; ++k) {
            av[m][k] = *(const short8*)(ar + k * 32);
            asm volatile("" : "+v"(av[m][k]));
        }
    }

    // ---- stage one 64-row j-tile: instr (wid,s) fills kg=wid*8+s slab ----
    auto stage = [&](int buf, int jt) {
        #pragma unroll
        for (int s = 0; s < 8; ++s) {
            const int kg = wid * 8 + s;
            const unsigned short* src = vn + (size_t)(jt + lane) * DIM + kg * 8;
            __builtin_amdgcn_global_load_lds((g_void*)src,
                (l_void*)&Bs[buf][kg][0][0], 16, 0, 0);
        }
    };

    float rs[4][4] = {};

    stage(0, j0);
    __syncthreads();

    int buf = 0;
    for (int js = 0; js < 16; ++js) {
        if (js < 15) stage(buf ^ 1, j0 + (js + 1) * 64);

        f32x4 acc[4][2];
        #pragma unroll
        for (int k = 0; k < 8; ++k) {
            const short8 b0 = *(const short8*)&Bs[buf][k * 4 + lg][wc * 32 + lr][0];
            const short8 b1 = *(const short8*)&Bs[buf][k * 4 + lg][wc * 32 + 16 + lr][0];
            if (k == 0) {
                const f32x4 z = {0.f, 0.f, 0.f, 0.f};
                #pragma unroll
                for (int m = 0; m < 4; ++m) {
                    acc[m][0] = __builtin_amdgcn_mfma_f32_16x16x32_bf16(av[m][0], b0, z, 0, 0, 0);
                    acc[m][1] = __builtin_amdgcn_mfma_f32_16x16x32_bf16(av[m][0], b1, z, 0, 0, 0);
                }
            } else {
                #pragma unroll
                for (int m = 0; m < 4; ++m) {
                    acc[m][0] = __builtin_amdgcn_mfma_f32_16x16x32_bf16(av[m][k], b0, acc[m][0], 0, 0, 0);
                    acc[m][1] = __builtin_amdgcn_mfma_f32_16x16x32_bf16(av[m][k], b1, acc[m][1], 0, 0, 0);
                }
            }
        }

        // acc is in log2 domain (scale folded into un) -> raw v_exp_f32
        #pragma unroll
        for (int m = 0; m < 4; ++m)
            #pragma unroll
            for (int n = 0; n < 2; ++n)
                #pragma unroll
                for (int r = 0; r < 4; ++r)
                    rs[m][r] += __builtin_amdgcn_exp2f(acc[m][n][r]);

        __syncthreads();
        buf ^= 1;
    }

    // ---- per-row reduce across the 16 col-lanes; C/D row = lg*4 + r ----
    #pragma unroll
    for (int m = 0; m < 4; ++m)
        #pragma unroll
        for (int r = 0; r < 4; ++r) {
            float s = rs[m][r];
            s += __shfl_xor(s, 1);
            s += __shfl_xor(s, 2);
            s += __shfl_xor(s, 4);
            s += __shfl_xor(s, 8);
            if (lr == 0)
                atomicAdd(&rowsum[i0 + wr * 64 + m * 16 + lg * 4 + r], s);
        }
}

// ---------------------------------------------------------------------------
// Kernel 3 (single block): out = mean(log(rowsum) - diag).
// ---------------------------------------------------------------------------
__global__ __launch_bounds__(1024) void finish_kernel(
    const float* __restrict__ rowsum, const float* __restrict__ diag,
    float* __restrict__ out)
{
    __shared__ float red[16];
    const int t    = threadIdx.x;
    const int lane = t & 63;
    const int wid  = t >> 6;

    float c = 0.0f;
    #pragma unroll
    for (int q = 0; q < 8; ++q) {
        const int r = t + 1024 * q;
        c += logf(rowsum[r]) - diag[r];
    }
    #pragma unroll
    for (int m = 32; m >= 1; m >>= 1) c += __shfl_xor(c, m);
    if (lane == 0) red[wid] = c;
    __syncthreads();
    if (t == 0) {
        float s = 0.0f;
        #pragma unroll
        for (int k = 0; k < 16; ++k) s += red[k];
        out[0] = s * (1.0f / (float)NROWS);
    }
}

// ---------------------------------------------------------------------------
extern "C" void kernel_launch(void* const* d_in, const int* in_sizes, int n_in,
                              void* d_out, int out_size, void* d_ws, size_t ws_size,
                              hipStream_t stream)
{
    const float* u = (const float*)d_in[0];
    const float* v = (const float*)d_in[1];
    float* out = (float*)d_out;

    char* w = (char*)d_ws;
    unsigned short* un = (unsigned short*)w;                                  // 4 MB
    unsigned short* vn = (unsigned short*)(w + (size_t)NROWS * DIM * 2);      // 4 MB
    float* diag   = (float*)(w + (size_t)NROWS * DIM * 4);                    // 32 KB
    float* rowsum = diag + NROWS;                                             // 32 KB

    norm_kernel<<<NROWS / 4, 256, 0, stream>>>(u, v, un, vn, diag, rowsum);
    gemm_kernel<<<512, 256, 0, stream>>>(un, vn, rowsum);
    finish_kernel<<<1, 1024, 0, stream>>>(rowsum, diag, out);
}

// Round 6
// 118.950 us; speedup vs baseline: 1.0386x; 1.0386x over previous
//
#include <hip/hip_runtime.h>
#include <hip/hip_bf16.h>
#include <math.h>

#define NROWS 8192
#define DIM   256
#define INV_T 14.285714285714286f   // 1/0.07
#define LOG2E_T 20.60992893360759f  // (1/0.07) * log2(e) -- folded into un
#define EPS_N 1e-8f

typedef __attribute__((ext_vector_type(8))) short short8;
typedef __attribute__((ext_vector_type(4))) float f32x4;

typedef const __attribute__((address_space(1))) void g_void;
typedef __attribute__((address_space(3))) void l_void;

__device__ inline unsigned short f2bf(float x) {
    __hip_bfloat16 h = __float2bfloat16(x);
    return __builtin_bit_cast(unsigned short, h);
}

// ---------------------------------------------------------------------------
// Kernel 1: per-row normalize. un scaled by 1/T*log2(e) (exp2 domain for the
// GEMM); vn plain normalized; diag logit fp32 (natural-log domain); zero rowsum.
// ---------------------------------------------------------------------------
__global__ __launch_bounds__(256) void norm_kernel(
    const float* __restrict__ u, const float* __restrict__ v,
    unsigned short* __restrict__ un, unsigned short* __restrict__ vn,
    float* __restrict__ diag, float* __restrict__ rowsum)
{
    if (threadIdx.x < 4) rowsum[blockIdx.x * 4 + threadIdx.x] = 0.0f;

    const int wid  = threadIdx.x >> 6;
    const int lane = threadIdx.x & 63;
    const int r    = blockIdx.x * 4 + wid;

    const float4* u4 = (const float4*)(u + (size_t)r * DIM);
    const float4* v4 = (const float4*)(v + (size_t)r * DIM);
    float4 a = u4[lane];
    float4 b = v4[lane];

    float ssu = a.x * a.x + a.y * a.y + a.z * a.z + a.w * a.w;
    float ssv = b.x * b.x + b.y * b.y + b.z * b.z + b.w * b.w;
    float duv = a.x * b.x + a.y * b.y + a.z * b.z + a.w * b.w;

    #pragma unroll
    for (int m = 32; m >= 1; m >>= 1) {
        ssu += __shfl_xor(ssu, m);
        ssv += __shfl_xor(ssv, m);
        duv += __shfl_xor(duv, m);
    }

    const float iu  = 1.0f / fmaxf(sqrtf(ssu), EPS_N);
    const float iv  = 1.0f / fmaxf(sqrtf(ssv), EPS_N);
    const float ius = iu * LOG2E_T;          // exp2-domain scale folded into un

    ushort4 pu, pv;
    pu.x = f2bf(a.x * ius); pu.y = f2bf(a.y * ius);
    pu.z = f2bf(a.z * ius); pu.w = f2bf(a.w * ius);
    pv.x = f2bf(b.x * iv);  pv.y = f2bf(b.y * iv);
    pv.z = f2bf(b.z * iv);  pv.w = f2bf(b.w * iv);
    *(ushort4*)(un + (size_t)r * DIM + 4 * lane) = pu;
    *(ushort4*)(vn + (size_t)r * DIM + 4 * lane) = pv;

    if (lane == 0) diag[r] = duv * iu * iv * INV_T;
}

// ---------------------------------------------------------------------------
// Kernel 2: flash-style. Block = 128 i-rows x 1024 j-cols (16 tiles of 64).
// A-frags loaded via INLINE-ASM global_load_dwordx4 ("=v" outputs): asm-defined
// values cannot be rematerialized, so the allocator must keep them resident
// (rounds 3-5 showed plain loads get remat'd/spilled -> 256KB/CU/j-step of L2
// A-traffic = the 9600cy/j-step bottleneck). The __syncthreads() below drains
// vmcnt(0) covering these loads; every MFMA depends on post-barrier ds_reads
// so none can hoist above the barrier.
// B tile staged via global_load_lds into k-chunked Bs[kg][row][8]
// (conflict-free b128 reads, measured 0 conflicts). Per wave per j-step:
// 16 ds_read_b128 + 64 MFMA + 32 exp2. One reduce+atomic per block.
// ---------------------------------------------------------------------------
__global__ __launch_bounds__(256, 2)
void gemm_kernel(
    const unsigned short* __restrict__ un, const unsigned short* __restrict__ vn,
    float* __restrict__ rowsum)
{
    __shared__ unsigned short Bs[2][32][64][8];   // 64 KB

    const int t    = threadIdx.x;
    const int lane = t & 63;
    const int wid  = t >> 6;
    const int wr   = wid >> 1;
    const int wc   = wid & 1;
    const int bid  = blockIdx.x;
    const int by   = bid & 7;          // XCD id -> j-panel pinned to one L2
    const int bx   = bid >> 3;
    const int i0   = bx * 128;
    const int j0   = by * 1024;

    const int lr = lane & 15;          // frag row (A) / frag col (B, C/D)
    const int lg = lane >> 4;          // k-group

    // ---- stage one 64-row j-tile: instr (wid,s) fills kg=wid*8+s slab ----
    auto stage = [&](int buf, int jt) {
        #pragma unroll
        for (int s = 0; s < 8; ++s) {
            const int kg = wid * 8 + s;
            const unsigned short* src = vn + (size_t)(jt + lane) * DIM + kg * 8;
            __builtin_amdgcn_global_load_lds((g_void*)src,
                (l_void*)&Bs[buf][kg][0][0], 16, 0, 0);
        }
    };

    stage(0, j0);

    // ---- A fragments: rows i0+wr*64+m*16+lr, k = k*32 + lg*8 .. +7 ----
    short8 av[4][8];
    #pragma unroll
    for (int m = 0; m < 4; ++m) {
        const unsigned short* ar =
            un + (size_t)(i0 + wr * 64 + m * 16 + lr) * DIM + lg * 8;
        #pragma unroll
        for (int k = 0; k < 8; ++k) {
            asm volatile("global_load_dwordx4 %0, %1, off"
                         : "=v"(av[m][k]) : "v"(ar + k * 32));
        }
    }

    float rs[4][4] = {};

    __syncthreads();   // drains vmcnt(0): av loads + stage(0) complete

    int buf = 0;
    #pragma unroll 1
    for (int js = 0; js < 16; ++js) {
        if (js < 15) stage(buf ^ 1, j0 + (js + 1) * 64);

        f32x4 acc[4][2];
        #pragma unroll
        for (int k = 0; k < 8; ++k) {
            const short8 b0 = *(const short8*)&Bs[buf][k * 4 + lg][wc * 32 + lr][0];
            const short8 b1 = *(const short8*)&Bs[buf][k * 4 + lg][wc * 32 + 16 + lr][0];
            if (k == 0) {
                const f32x4 z = {0.f, 0.f, 0.f, 0.f};
                #pragma unroll
                for (int m = 0; m < 4; ++m) {
                    acc[m][0] = __builtin_amdgcn_mfma_f32_16x16x32_bf16(av[m][0], b0, z, 0, 0, 0);
                    acc[m][1] = __builtin_amdgcn_mfma_f32_16x16x32_bf16(av[m][0], b1, z, 0, 0, 0);
                }
            } else {
                #pragma unroll
                for (int m = 0; m < 4; ++m) {
                    acc[m][0] = __builtin_amdgcn_mfma_f32_16x16x32_bf16(av[m][k], b0, acc[m][0], 0, 0, 0);
                    acc[m][1] = __builtin_amdgcn_mfma_f32_16x16x32_bf16(av[m][k], b1, acc[m][1], 0, 0, 0);
                }
            }
        }

        // acc is in log2 domain (scale folded into un) -> raw v_exp_f32
        #pragma unroll
        for (int m = 0; m < 4; ++m)
            #pragma unroll
            for (int n = 0; n < 2; ++n)
                #pragma unroll
                for (int r = 0; r < 4; ++r)
                    rs[m][r] += __builtin_amdgcn_exp2f(acc[m][n][r]);

        __syncthreads();
        buf ^= 1;
    }

    // ---- per-row reduce across the 16 col-lanes; C/D row = lg*4 + r ----
    #pragma unroll
    for (int m = 0; m < 4; ++m)
        #pragma unroll
        for (int r = 0; r < 4; ++r) {
            float s = rs[m][r];
            s += __shfl_xor(s, 1);
            s += __shfl_xor(s, 2);
            s += __shfl_xor(s, 4);
            s += __shfl_xor(s, 8);
            if (lr == 0)
                atomicAdd(&rowsum[i0 + wr * 64 + m * 16 + lg * 4 + r], s);
        }
}

// ---------------------------------------------------------------------------
// Kernel 3 (single block): out = mean(log(rowsum) - diag).
// ---------------------------------------------------------------------------
__global__ __launch_bounds__(1024) void finish_kernel(
    const float* __restrict__ rowsum, const float* __restrict__ diag,
    float* __restrict__ out)
{
    __shared__ float red[16];
    const int t    = threadIdx.x;
    const int lane = t & 63;
    const int wid  = t >> 6;

    float c = 0.0f;
    #pragma unroll
    for (int q = 0; q < 8; ++q) {
        const int r = t + 1024 * q;
        c += logf(rowsum[r]) - diag[r];
    }
    #pragma unroll
    for (int m = 32; m >= 1; m >>= 1) c += __shfl_xor(c, m);
    if (lane == 0) red[wid] = c;
    __syncthreads();
    if (t == 0) {
        float s = 0.0f;
        #pragma unroll
        for (int k = 0; k < 16; ++k) s += red[k];
        out[0] = s * (1.0f / (float)NROWS);
    }
}

// ---------------------------------------------------------------------------
extern "C" void kernel_launch(void* const* d_in, const int* in_sizes, int n_in,
                              void* d_out, int out_size, void* d_ws, size_t ws_size,
                              hipStream_t stream)
{
    const float* u = (const float*)d_in[0];
    const float* v = (const float*)d_in[1];
    float* out = (float*)d_out;

    char* w = (char*)d_ws;
    unsigned short* un = (unsigned short*)w;                                  // 4 MB
    unsigned short* vn = (unsigned short*)(w + (size_t)NROWS * DIM * 2);      // 4 MB
    float* diag   = (float*)(w + (size_t)NROWS * DIM * 4);                    // 32 KB
    float* rowsum = diag + NROWS;                                             // 32 KB

    norm_kernel<<<NROWS / 4, 256, 0, stream>>>(u, v, un, vn, diag, rowsum);
    gemm_kernel<<<512, 256, 0, stream>>>(un, vn, rowsum);
    finish_kernel<<<1, 1024, 0, stream>>>(rowsum, diag, out);
}